// Round 1
// baseline (421.667 us; speedup 1.0000x reference)
//
#include <hip/hip_runtime.h>
#include <hip/hip_bf16.h>

// Problem constants (match reference)
static constexpr int KD  = 64;    // feature dim
static constexpr int KIN = 256;   // concat dim
static constexpr int KH  = 64;    // hidden dim

typedef __attribute__((ext_vector_type(8))) short bf16x8;
typedef __attribute__((ext_vector_type(4))) float f32x4;

__device__ inline unsigned short f2bf(float f) {
  union { float f; unsigned u; } uf; uf.f = f;
  unsigned u = uf.u;
  return (unsigned short)((u + 0x7FFFu + ((u >> 16) & 1u)) >> 16);
}

__device__ inline bf16x8 pack8(const float* p) {
  float4 lo = *(const float4*)p;
  float4 hi = *(const float4*)(p + 4);
  bf16x8 v;
  v[0] = (short)f2bf(lo.x); v[1] = (short)f2bf(lo.y);
  v[2] = (short)f2bf(lo.z); v[3] = (short)f2bf(lo.w);
  v[4] = (short)f2bf(hi.x); v[5] = (short)f2bf(hi.y);
  v[6] = (short)f2bf(hi.z); v[7] = (short)f2bf(hi.w);
  return v;
}

__device__ inline float sigm(float x) { return 1.0f / (1.0f + __expf(-x)); }
__device__ inline float silu_(float x) { return x * sigm(x); }

// K0: convert + transpose weights to bf16 (B^T layout: [n][k])
__global__ void k_prep(const float* __restrict__ wc1, const float* __restrict__ wg1,
                       const float* __restrict__ wc2, const float* __restrict__ wg2,
                       const float* __restrict__ wo,
                       unsigned short* __restrict__ wc1t, unsigned short* __restrict__ wg1t,
                       unsigned short* __restrict__ wc2t, unsigned short* __restrict__ wg2t,
                       unsigned short* __restrict__ wot) {
  int t = blockIdx.x * blockDim.x + threadIdx.x;
  if (t < KIN * KH) {
    int n = t >> 8, k = t & 255;                 // wc1t[n*256+k] = Wc1[k][n]
    wc1t[t] = f2bf(wc1[k * KH + n]);
    wg1t[t] = f2bf(wg1[k * KH + n]);
  }
  if (t < KH * KD) {
    int n = t >> 6, k = t & 63;
    wc2t[t] = f2bf(wc2[k * KD + n]);
    wg2t[t] = f2bf(wg2[k * KD + n]);
    wot[t]  = f2bf(wo[k * KD + n]);
  }
}

// K1: per-angle MLPs + gated product + atomic scatter into agg (= d_out)
__global__ __launch_bounds__(256) void k_angle(
    const float* __restrict__ atom, const float* __restrict__ bond,
    const float* __restrict__ bwt,  const float* __restrict__ ang,
    const int* __restrict__ bgr,
    const unsigned short* __restrict__ wc1t, const unsigned short* __restrict__ wg1t,
    const unsigned short* __restrict__ wc2t, const unsigned short* __restrict__ wg2t,
    const float* __restrict__ bc1, const float* __restrict__ bc2,
    const float* __restrict__ bg1, const float* __restrict__ bg2,
    float* __restrict__ agg, int ng) {
  constexpr int HS = 68;  // padded LDS row stride (floats): 2-way banks, 16B aligned
  __shared__ float hbc[4][16 * HS];
  __shared__ float hbg[4][16 * HS];
  __shared__ float wbuf[4][16 * HS];
  __shared__ int ibuf[4][16];

  const int wave = threadIdx.x >> 6;
  const int lane = threadIdx.x & 63;
  const int r15 = lane & 15;
  const int ck = lane >> 4;

  const int gbase = blockIdx.x * 64 + wave * 16;
  const int gi = gbase + r15;
  const bool valid = gi < ng;
  const int g = valid ? gi : 0;
  const int ci = bgr[3 * g + 0];
  const int bi = bgr[3 * g + 1];
  const int bj = bgr[3 * g + 2];

  // bond-weight product for this row (lane covers d in [ck*16, ck*16+16))
  {
    const float* wa = bwt + (long)bi * KD;
    const float* wb = bwt + (long)bj * KD;
    const int d0 = ck * 16;
#pragma unroll
    for (int i = 0; i < 4; i++) {
      float4 a4 = *(const float4*)(wa + d0 + i * 4);
      float4 b4 = *(const float4*)(wb + d0 + i * 4);
      float4 pr = make_float4(a4.x * b4.x, a4.y * b4.y, a4.z * b4.z, a4.w * b4.w);
      *(float4*)(&wbuf[wave][r15 * HS + d0 + i * 4]) = pr;
    }
    if (ck == 0) ibuf[wave][r15] = valid ? bi : -1;
  }

  // gather A fragments: total[row][k], 8 contiguous k per lane
  bf16x8 a1[8];
  {
    const float* p0 = bond + (long)bi * KD;
    const float* p1 = bond + (long)bj * KD;
    const float* p2 = ang + (long)g * KD;
    const float* p3 = atom + (long)ci * KD;
    const int off8 = ck * 8;
    a1[0] = pack8(p0 + off8);      a1[1] = pack8(p0 + 32 + off8);
    a1[2] = pack8(p1 + off8);      a1[3] = pack8(p1 + 32 + off8);
    a1[4] = pack8(p2 + off8);      a1[5] = pack8(p2 + 32 + off8);
    a1[6] = pack8(p3 + off8);      a1[7] = pack8(p3 + 32 + off8);
  }

  // GEMM1: hidden = total @ W1 + b1  (both core and gate)
  f32x4 ac[4], ag[4];
#pragma unroll
  for (int n = 0; n < 4; n++) {
    float b1 = bc1[n * 16 + r15];
    float b2 = bg1[n * 16 + r15];
    ac[n] = (f32x4){b1, b1, b1, b1};
    ag[n] = (f32x4){b2, b2, b2, b2};
  }
#pragma unroll
  for (int s = 0; s < 8; s++) {
    const int koff = s * 32 + ck * 8;
#pragma unroll
    for (int n = 0; n < 4; n++) {
      bf16x8 b_c = *(const bf16x8*)(wc1t + (n * 16 + r15) * KIN + koff);
      bf16x8 b_g = *(const bf16x8*)(wg1t + (n * 16 + r15) * KIN + koff);
      ac[n] = __builtin_amdgcn_mfma_f32_16x16x32_bf16(a1[s], b_c, ac[n], 0, 0, 0);
      ag[n] = __builtin_amdgcn_mfma_f32_16x16x32_bf16(a1[s], b_g, ag[n], 0, 0, 0);
    }
  }

  // silu + stage hidden to LDS (transpose for GEMM2 A-fragments)
#pragma unroll
  for (int n = 0; n < 4; n++) {
#pragma unroll
    for (int j = 0; j < 4; j++) {
      const int row = ck * 4 + j;
      const int h = n * 16 + r15;
      hbc[wave][row * HS + h] = silu_(ac[n][j]);
      hbg[wave][row * HS + h] = silu_(ag[n][j]);
    }
  }
  __syncthreads();

  // GEMM2: out = hidden @ W2 + b2
  bf16x8 a2c[2], a2g[2];
#pragma unroll
  for (int s = 0; s < 2; s++) {
    const int h0 = s * 32 + ck * 8;
    a2c[s] = pack8(&hbc[wave][r15 * HS + h0]);
    a2g[s] = pack8(&hbg[wave][r15 * HS + h0]);
  }
  f32x4 oc[4], og[4];
#pragma unroll
  for (int n = 0; n < 4; n++) {
    float b1 = bc2[n * 16 + r15];
    float b2 = bg2[n * 16 + r15];
    oc[n] = (f32x4){b1, b1, b1, b1};
    og[n] = (f32x4){b2, b2, b2, b2};
  }
#pragma unroll
  for (int s = 0; s < 2; s++) {
    const int koff = s * 32 + ck * 8;
#pragma unroll
    for (int n = 0; n < 4; n++) {
      bf16x8 b_c = *(const bf16x8*)(wc2t + (n * 16 + r15) * KH + koff);
      bf16x8 b_g = *(const bf16x8*)(wg2t + (n * 16 + r15) * KH + koff);
      oc[n] = __builtin_amdgcn_mfma_f32_16x16x32_bf16(a2c[s], b_c, oc[n], 0, 0, 0);
      og[n] = __builtin_amdgcn_mfma_f32_16x16x32_bf16(a2g[s], b_g, og[n], 0, 0, 0);
    }
  }

  // epilogue: upd = silu(oc) * sigmoid(og) * bw[bi]*bw[bj]; scatter-add to agg[bi]
#pragma unroll
  for (int n = 0; n < 4; n++) {
#pragma unroll
    for (int j = 0; j < 4; j++) {
      const int row = ck * 4 + j;
      const int bia = ibuf[wave][row];
      if (bia >= 0) {
        const int d = n * 16 + r15;
        const float core = silu_(oc[n][j]);
        const float gate = sigm(og[n][j]);
        const float w = wbuf[wave][row * HS + d];
        atomicAdd(agg + (long)bia * KD + d, core * gate * w);
      }
    }
  }
}

// K2: out = agg @ Wo + bo + bond_feas   (in-place on d_out; each wave owns 16 rows)
__global__ __launch_bounds__(256) void k_out(
    const float* __restrict__ bond, const unsigned short* __restrict__ wot,
    const float* __restrict__ bo, float* __restrict__ out, int nb) {
  const int wave = threadIdx.x >> 6;
  const int lane = threadIdx.x & 63;
  const int r15 = lane & 15;
  const int ck = lane >> 4;
  const long rbase = (long)blockIdx.x * 64 + wave * 16;

  const long row = rbase + r15;
  const long rowc = (row < nb) ? row : 0;
  bf16x8 a[2];
  a[0] = pack8(out + rowc * KD + ck * 8);
  a[1] = pack8(out + rowc * KD + 32 + ck * 8);

  f32x4 acc[4];
#pragma unroll
  for (int n = 0; n < 4; n++) {
    float b = bo[n * 16 + r15];
    acc[n] = (f32x4){b, b, b, b};
  }
#pragma unroll
  for (int s = 0; s < 2; s++) {
    const int koff = s * 32 + ck * 8;
#pragma unroll
    for (int n = 0; n < 4; n++) {
      bf16x8 bf = *(const bf16x8*)(wot + (n * 16 + r15) * KH + koff);
      acc[n] = __builtin_amdgcn_mfma_f32_16x16x32_bf16(a[s], bf, acc[n], 0, 0, 0);
    }
  }
#pragma unroll
  for (int n = 0; n < 4; n++) {
#pragma unroll
    for (int j = 0; j < 4; j++) {
      const long orow = rbase + ck * 4 + j;
      if (orow < nb) {
        const int d = n * 16 + r15;
        out[orow * KD + d] = acc[n][j] + bond[orow * KD + d];
      }
    }
  }
}

extern "C" void kernel_launch(void* const* d_in, const int* in_sizes, int n_in,
                              void* d_out, int out_size, void* d_ws, size_t ws_size,
                              hipStream_t stream) {
  const float* atom = (const float*)d_in[0];
  const float* bond = (const float*)d_in[1];
  const float* bwt  = (const float*)d_in[2];
  const float* ang  = (const float*)d_in[3];
  const int*   bgr  = (const int*)d_in[4];
  const float* wc1 = (const float*)d_in[5];
  const float* bc1 = (const float*)d_in[6];
  const float* wc2 = (const float*)d_in[7];
  const float* bc2 = (const float*)d_in[8];
  const float* wg1 = (const float*)d_in[9];
  const float* bg1 = (const float*)d_in[10];
  const float* wg2 = (const float*)d_in[11];
  const float* bg2 = (const float*)d_in[12];
  const float* wo  = (const float*)d_in[13];
  const float* bo  = (const float*)d_in[14];

  const int nb = in_sizes[1] / KD;   // bonds
  const int ng = in_sizes[4] / 3;    // angles

  float* out = (float*)d_out;

  // bf16 transposed weights in workspace
  unsigned short* wc1t = (unsigned short*)d_ws;
  unsigned short* wg1t = wc1t + KIN * KH;
  unsigned short* wc2t = wg1t + KIN * KH;
  unsigned short* wg2t = wc2t + KH * KD;
  unsigned short* wot  = wg2t + KH * KD;

  // zero the aggregation buffer (d_out doubles as agg accumulator)
  hipMemsetAsync(d_out, 0, (size_t)out_size * sizeof(float), stream);

  k_prep<<<(KIN * KH + 255) / 256, 256, 0, stream>>>(wc1, wg1, wc2, wg2, wo,
                                                     wc1t, wg1t, wc2t, wg2t, wot);

  const int ablocks = (ng + 63) / 64;
  k_angle<<<ablocks, 256, 0, stream>>>(atom, bond, bwt, ang, bgr,
                                       wc1t, wg1t, wc2t, wg2t,
                                       bc1, bc2, bg1, bg2, out, ng);

  const int oblocks = (nb + 63) / 64;
  k_out<<<oblocks, 256, 0, stream>>>(bond, wot, bo, out, nb);
}

// Round 2
// 404.180 us; speedup vs baseline: 1.0433x; 1.0433x over previous
//
#include <hip/hip_runtime.h>
#include <hip/hip_bf16.h>

// Problem constants (match reference)
static constexpr int KD  = 64;    // feature dim
static constexpr int KIN = 256;   // concat dim
static constexpr int KH  = 64;    // hidden dim

typedef __attribute__((ext_vector_type(8))) short bf16x8;
typedef __attribute__((ext_vector_type(4))) float f32x4;

__device__ inline unsigned short f2bf(float f) {
  union { float f; unsigned u; } uf; uf.f = f;
  unsigned u = uf.u;
  return (unsigned short)((u + 0x7FFFu + ((u >> 16) & 1u)) >> 16);
}

__device__ inline bf16x8 pack8(const float* p) {
  float4 lo = *(const float4*)p;
  float4 hi = *(const float4*)(p + 4);
  bf16x8 v;
  v[0] = (short)f2bf(lo.x); v[1] = (short)f2bf(lo.y);
  v[2] = (short)f2bf(lo.z); v[3] = (short)f2bf(lo.w);
  v[4] = (short)f2bf(hi.x); v[5] = (short)f2bf(hi.y);
  v[6] = (short)f2bf(hi.z); v[7] = (short)f2bf(hi.w);
  return v;
}

__device__ inline float sigm(float x) { return 1.0f / (1.0f + __expf(-x)); }
__device__ inline float silu_(float x) { return x * sigm(x); }

// Hardware f32 atomic add, fire-and-forget (no CAS loop, no return, no wait).
__device__ inline void atomic_fadd(float* p, float v) {
  asm volatile("global_atomic_add_f32 %0, %1, off" :: "v"(p), "v"(v) : "memory");
}

// K0: convert + transpose weights to bf16 (B^T layout: [n][k])
__global__ void k_prep(const float* __restrict__ wc1, const float* __restrict__ wg1,
                       const float* __restrict__ wc2, const float* __restrict__ wg2,
                       const float* __restrict__ wo,
                       unsigned short* __restrict__ wc1t, unsigned short* __restrict__ wg1t,
                       unsigned short* __restrict__ wc2t, unsigned short* __restrict__ wg2t,
                       unsigned short* __restrict__ wot) {
  int t = blockIdx.x * blockDim.x + threadIdx.x;
  if (t < KIN * KH) {
    int n = t >> 8, k = t & 255;                 // wc1t[n*256+k] = Wc1[k][n]
    wc1t[t] = f2bf(wc1[k * KH + n]);
    wg1t[t] = f2bf(wg1[k * KH + n]);
  }
  if (t < KH * KD) {
    int n = t >> 6, k = t & 63;
    wc2t[t] = f2bf(wc2[k * KD + n]);
    wg2t[t] = f2bf(wg2[k * KD + n]);
    wot[t]  = f2bf(wo[k * KD + n]);
  }
}

// K1: per-angle MLPs + gated product + HW-atomic scatter into agg (= d_out)
__global__ __launch_bounds__(256) void k_angle(
    const float* __restrict__ atom, const float* __restrict__ bond,
    const float* __restrict__ bwt,  const float* __restrict__ ang,
    const int* __restrict__ bgr,
    const unsigned short* __restrict__ wc1t, const unsigned short* __restrict__ wg1t,
    const unsigned short* __restrict__ wc2t, const unsigned short* __restrict__ wg2t,
    const float* __restrict__ bc1, const float* __restrict__ bc2,
    const float* __restrict__ bg1, const float* __restrict__ bg2,
    float* __restrict__ agg, int ng) {
  constexpr int HS = 72;  // padded LDS row stride (shorts): 16B-aligned rows, 2-way banks
  __shared__ unsigned short hbc[4][16 * HS];
  __shared__ unsigned short hbg[4][16 * HS];

  const int wave = threadIdx.x >> 6;
  const int lane = threadIdx.x & 63;
  const int r15 = lane & 15;
  const int ck = lane >> 4;

  const int gi = blockIdx.x * 64 + wave * 16 + r15;
  const bool valid = gi < ng;
  const int g = valid ? gi : 0;
  const int ci = bgr[3 * g + 0];
  const int bi = bgr[3 * g + 1];
  const int bj = bgr[3 * g + 2];
  const int biv = valid ? bi : -1;   // row-validity + scatter target, canonical on lanes 0..15

  // gather A fragments: total[row][k], 8 contiguous k per lane
  bf16x8 a1[8];
  {
    const float* p0 = bond + (long)bi * KD;
    const float* p1 = bond + (long)bj * KD;
    const float* p2 = ang + (long)g * KD;
    const float* p3 = atom + (long)ci * KD;
    const int off8 = ck * 8;
    a1[0] = pack8(p0 + off8);      a1[1] = pack8(p0 + 32 + off8);
    a1[2] = pack8(p1 + off8);      a1[3] = pack8(p1 + 32 + off8);
    a1[4] = pack8(p2 + off8);      a1[5] = pack8(p2 + 32 + off8);
    a1[6] = pack8(p3 + off8);      a1[7] = pack8(p3 + 32 + off8);
  }

  // GEMM1: hidden = total @ W1 + b1  (core and gate)
  f32x4 ac[4], ag[4];
#pragma unroll
  for (int n = 0; n < 4; n++) {
    float b1 = bc1[n * 16 + r15];
    float b2 = bg1[n * 16 + r15];
    ac[n] = (f32x4){b1, b1, b1, b1};
    ag[n] = (f32x4){b2, b2, b2, b2};
  }
#pragma unroll
  for (int s = 0; s < 8; s++) {
    const int koff = s * 32 + ck * 8;
#pragma unroll
    for (int n = 0; n < 4; n++) {
      bf16x8 b_c = *(const bf16x8*)(wc1t + (n * 16 + r15) * KIN + koff);
      bf16x8 b_g = *(const bf16x8*)(wg1t + (n * 16 + r15) * KIN + koff);
      ac[n] = __builtin_amdgcn_mfma_f32_16x16x32_bf16(a1[s], b_c, ac[n], 0, 0, 0);
      ag[n] = __builtin_amdgcn_mfma_f32_16x16x32_bf16(a1[s], b_g, ag[n], 0, 0, 0);
    }
  }

  // silu + stage hidden to LDS as bf16 (transpose for GEMM2 A-fragments)
#pragma unroll
  for (int n = 0; n < 4; n++) {
#pragma unroll
    for (int j = 0; j < 4; j++) {
      const int row = ck * 4 + j;
      const int h = n * 16 + r15;
      hbc[wave][row * HS + h] = f2bf(silu_(ac[n][j]));
      hbg[wave][row * HS + h] = f2bf(silu_(ag[n][j]));
    }
  }
  __syncthreads();

  // GEMM2: out = hidden @ W2 + b2 (A-fragments read directly as bf16)
  bf16x8 a2c[2], a2g[2];
#pragma unroll
  for (int s = 0; s < 2; s++) {
    const int h0 = s * 32 + ck * 8;
    a2c[s] = *(const bf16x8*)(&hbc[wave][r15 * HS + h0]);
    a2g[s] = *(const bf16x8*)(&hbg[wave][r15 * HS + h0]);
  }
  f32x4 oc[4], og[4];
#pragma unroll
  for (int n = 0; n < 4; n++) {
    float b1 = bc2[n * 16 + r15];
    float b2 = bg2[n * 16 + r15];
    oc[n] = (f32x4){b1, b1, b1, b1};
    og[n] = (f32x4){b2, b2, b2, b2};
  }
#pragma unroll
  for (int s = 0; s < 2; s++) {
    const int koff = s * 32 + ck * 8;
#pragma unroll
    for (int n = 0; n < 4; n++) {
      bf16x8 b_c = *(const bf16x8*)(wc2t + (n * 16 + r15) * KH + koff);
      bf16x8 b_g = *(const bf16x8*)(wg2t + (n * 16 + r15) * KH + koff);
      oc[n] = __builtin_amdgcn_mfma_f32_16x16x32_bf16(a2c[s], b_c, oc[n], 0, 0, 0);
      og[n] = __builtin_amdgcn_mfma_f32_16x16x32_bf16(a2g[s], b_g, og[n], 0, 0, 0);
    }
  }

  // epilogue: upd = silu(oc) * sigmoid(og) * bw[bi]*bw[bj]; HW-atomic scatter to agg[bi]
#pragma unroll
  for (int j = 0; j < 4; j++) {
    const int row = ck * 4 + j;
    const int bia = __shfl(biv, row);
    const int bja = __shfl(bj, row);
    if (bia >= 0) {
      const float* wa = bwt + (long)bia * KD;
      const float* wb = bwt + (long)bja * KD;
      float* dst = agg + (long)bia * KD;
#pragma unroll
      for (int n = 0; n < 4; n++) {
        const int d = n * 16 + r15;
        const float w = wa[d] * wb[d];
        const float core = silu_(oc[n][j]);
        const float gate = sigm(og[n][j]);
        atomic_fadd(dst + d, core * gate * w);
      }
    }
  }
}

// K2: out = agg @ Wo + bo + bond_feas   (in-place on d_out; each wave owns 16 rows)
__global__ __launch_bounds__(256) void k_out(
    const float* __restrict__ bond, const unsigned short* __restrict__ wot,
    const float* __restrict__ bo, float* __restrict__ out, int nb) {
  const int wave = threadIdx.x >> 6;
  const int lane = threadIdx.x & 63;
  const int r15 = lane & 15;
  const int ck = lane >> 4;
  const long rbase = (long)blockIdx.x * 64 + wave * 16;

  const long row = rbase + r15;
  const long rowc = (row < nb) ? row : 0;
  bf16x8 a[2];
  a[0] = pack8(out + rowc * KD + ck * 8);
  a[1] = pack8(out + rowc * KD + 32 + ck * 8);

  f32x4 acc[4];
#pragma unroll
  for (int n = 0; n < 4; n++) {
    float b = bo[n * 16 + r15];
    acc[n] = (f32x4){b, b, b, b};
  }
#pragma unroll
  for (int s = 0; s < 2; s++) {
    const int koff = s * 32 + ck * 8;
#pragma unroll
    for (int n = 0; n < 4; n++) {
      bf16x8 bf = *(const bf16x8*)(wot + (n * 16 + r15) * KH + koff);
      acc[n] = __builtin_amdgcn_mfma_f32_16x16x32_bf16(a[s], bf, acc[n], 0, 0, 0);
    }
  }
#pragma unroll
  for (int n = 0; n < 4; n++) {
#pragma unroll
    for (int j = 0; j < 4; j++) {
      const long orow = rbase + ck * 4 + j;
      if (orow < nb) {
        const int d = n * 16 + r15;
        out[orow * KD + d] = acc[n][j] + bond[orow * KD + d];
      }
    }
  }
}

extern "C" void kernel_launch(void* const* d_in, const int* in_sizes, int n_in,
                              void* d_out, int out_size, void* d_ws, size_t ws_size,
                              hipStream_t stream) {
  const float* atom = (const float*)d_in[0];
  const float* bond = (const float*)d_in[1];
  const float* bwt  = (const float*)d_in[2];
  const float* ang  = (const float*)d_in[3];
  const int*   bgr  = (const int*)d_in[4];
  const float* wc1 = (const float*)d_in[5];
  const float* bc1 = (const float*)d_in[6];
  const float* wc2 = (const float*)d_in[7];
  const float* bc2 = (const float*)d_in[8];
  const float* wg1 = (const float*)d_in[9];
  const float* bg1 = (const float*)d_in[10];
  const float* wg2 = (const float*)d_in[11];
  const float* bg2 = (const float*)d_in[12];
  const float* wo  = (const float*)d_in[13];
  const float* bo  = (const float*)d_in[14];

  const int nb = in_sizes[1] / KD;   // bonds
  const int ng = in_sizes[4] / 3;    // angles

  float* out = (float*)d_out;

  // bf16 transposed weights in workspace
  unsigned short* wc1t = (unsigned short*)d_ws;
  unsigned short* wg1t = wc1t + KIN * KH;
  unsigned short* wc2t = wg1t + KIN * KH;
  unsigned short* wg2t = wc2t + KH * KD;
  unsigned short* wot  = wg2t + KH * KD;

  // zero the aggregation buffer (d_out doubles as agg accumulator)
  hipMemsetAsync(d_out, 0, (size_t)out_size * sizeof(float), stream);

  k_prep<<<(KIN * KH + 255) / 256, 256, 0, stream>>>(wc1, wg1, wc2, wg2, wo,
                                                     wc1t, wg1t, wc2t, wg2t, wot);

  const int ablocks = (ng + 63) / 64;
  k_angle<<<ablocks, 256, 0, stream>>>(atom, bond, bwt, ang, bgr,
                                       wc1t, wg1t, wc2t, wg2t,
                                       bc1, bc2, bg1, bg2, out, ng);

  const int oblocks = (nb + 63) / 64;
  k_out<<<oblocks, 256, 0, stream>>>(bond, wot, bo, out, nb);
}